// Round 12
// baseline (298.727 us; speedup 1.0000x reference)
//
#include <hip/hip_runtime.h>
#include <stdint.h>

#define N_SRC  200000
#define N_DST0 50000
#define N_DST1 10000
#define E0_N   800000
#define E1_N   320000
#define E_TOT  (E0_N + E1_N)
#define NSEG   (N_DST0 + N_DST1)
#define IN_C   128
#define HID    64
#define H0_N   4
#define C0     256      // H0*HID
#define OUTC   40
#define H1W    48       // padded h1 width
#define NEG_SLOPE 0.2f
#define BN_EPS 1e-5f

#define DCAP0  64                  // per-dst slab, avg deg 16 (Poisson)
#define DCAP1  96                  // per-dst slab, avg deg 32

#define NB_GEMM (N_SRC / 64)       // 3125
#define NB_SCAT ((E_TOT + 2047) / 2048)   // 547 (8 edges/thread)
#define GRID_K2 (8 * NB_SCAT)      // 4376: period-8 interleave, slot 7 = scatter

#define STG_P  264                 // store-stage row pitch (ushorts): 528B, 16B-aligned

typedef __attribute__((ext_vector_type(8))) short short8;
typedef __attribute__((ext_vector_type(4))) float f32x4;
typedef __attribute__((ext_vector_type(4))) unsigned short u16x4;

__device__ __forceinline__ float bf2f(unsigned short u){
  union{unsigned int i; float f;} v; v.i = ((unsigned int)u) << 16; return v.f;
}
__device__ __forceinline__ unsigned short f2bf(float f){   // RNE (weights only)
  union{float f; unsigned int i;} v; v.f = f;
  unsigned int u = v.i;
  unsigned int r = (u + 0x7FFFu + ((u >> 16) & 1u)) >> 16;
  return (unsigned short)r;
}
// truncate-pack two f32 -> one u32 of 2 bf16
__device__ __forceinline__ unsigned int pkt(float a, float b){
  return (__float_as_uint(a) >> 16) | (__float_as_uint(b) & 0xFFFF0000u);
}
__device__ __forceinline__ unsigned short tbf(float f){
  return (unsigned short)(__float_as_uint(f) >> 16);
}
__device__ __forceinline__ float lrelu(float x){ return x > 0.f ? x : NEG_SLOPE * x; }

// ---------------- K1: weight prep ----------------
__global__ void prep_all(const float* __restrict__ W0, const float* __restrict__ W1,
                         const float* __restrict__ as0a, const float* __restrict__ ad0a,
                         const float* __restrict__ as1a, const float* __restrict__ ad1a,
                         unsigned short* __restrict__ wt0, unsigned short* __restrict__ w1t,
                         unsigned short* __restrict__ waG, unsigned short* __restrict__ wa1G)
{
  int b = blockIdx.x, t = threadIdx.x;
  if (b < 128){                       // wt0: 256x128
    int idx = b * 256 + t;
    int n = idx / IN_C, k = idx % IN_C;
    wt0[idx] = f2bf(W0[k * C0 + n]);
  } else if (b < 176){                // w1t: 48x256
    int idx = (b - 128) * 256 + t;
    int n = idx / C0, k = idx % C0;
    w1t[idx] = (n < OUTC) ? f2bf(W1[k * OUTC + n]) : (unsigned short)0;
  } else {                            // waG 8x128, wa1G 2x256
    int idx = (b - 176) * 256 + t;
    if (idx < 1024){
      int k = idx >> 3, j = idx & 7, h = j & 3;
      const float* att = (j < 4) ? as0a : ad0a;
      float s = 0.f;
      #pragma unroll
      for (int c = 0; c < HID; c++) s += W0[k * C0 + h * HID + c] * att[h * HID + c];
      waG[j * IN_C + k] = f2bf(s);
    } else if (idx < 1536){
      int r = idx - 1024; int k = r >> 1, j = r & 1;
      const float* att = j ? ad1a : as1a;
      float s = 0.f;
      #pragma unroll
      for (int c = 0; c < OUTC; c++) s += W1[k * OUTC + c] * att[c];
      wa1G[j * C0 + k] = f2bf(s);
    }
  }
}

// ---------------- K2: gemm0 (7/8 of slots) || slab-scatter (1/8, 8 edges/thread) ----------------
__global__ __launch_bounds__(256) void gemm0_bucket_kernel(
    const float* __restrict__ x, const unsigned short* __restrict__ wt0,
    const unsigned short* __restrict__ waG,
    unsigned short* __restrict__ h0, float* __restrict__ as0, float* __restrict__ ad0,
    const int* __restrict__ esrc0, const int* __restrict__ edst0,
    const int* __restrict__ esrc1, const int* __restrict__ edst1,
    int* __restrict__ bcnt, int* __restrict__ pairs0, int* __restrict__ pairs1)
{
  __shared__ __align__(16) unsigned short aT[64 * 136];   // 17408 B; reused as 32xSTG_P store stage (16896 B)
  int b = blockIdx.x;
  int tid = threadIdx.x;

  if ((b & 7) == 7){
    // ---- scatter role: 8 edges/thread for deep MLP ----
    int base = (b >> 3) * 2048 + tid;
    int dk[8], sk[8];
    bool ok[8], l0[8];
    #pragma unroll
    for (int k = 0; k < 8; k++){
      int e = base + k * 256;
      ok[k] = e < E_TOT;
      l0[k] = e < E0_N;
      if (ok[k]){
        if (l0[k]){ dk[k] = edst0[e]; sk[k] = esrc0[e]; }
        else      { int i = e - E0_N; dk[k] = edst1[i]; sk[k] = esrc1[i]; }
      }
    }
    #pragma unroll
    for (int k = 0; k < 8; k++){
      if (ok[k]){
        if (l0[k]){
          int pos = atomicAdd(&bcnt[dk[k]], 1);
          if (pos < DCAP0) pairs0[dk[k] * DCAP0 + pos] = sk[k];
        } else {
          int pos = atomicAdd(&bcnt[N_DST0 + dk[k]], 1);
          if (pos < DCAP1) pairs1[dk[k] * DCAP1 + pos] = sk[k];
        }
      }
    }
    return;
  }
  // ---- gemm role ----
  int g = (b >> 3) * 7 + (b & 7);     // dense index over non-scatter slots
  if (g >= NB_GEMM) return;
  int w = tid >> 6, lane = tid & 63, lo = lane & 15, hi = lane >> 4;
  int r0 = g * 64;

  // B fragments: wave w owns head w (cols w*64 .. w*64+63)
  short8 B[4][4];
  #pragma unroll
  for (int nf = 0; nf < 4; nf++)
    #pragma unroll
    for (int kf = 0; kf < 4; kf++)
      B[nf][kf] = *(const short8*)&wt0[(w * 64 + nf * 16 + lo) * IN_C + kf * 32 + hi * 8];
  short8 WA[4];
  {
    short8 z8 = {0,0,0,0,0,0,0,0};
    #pragma unroll
    for (int kf = 0; kf < 4; kf++)
      WA[kf] = (w == 0 && lo < 8) ? *(const short8*)&waG[lo * IN_C + kf * 32 + hi * 8] : z8;
  }
  // stage A in two pf[4] rounds (lower VGPR peak)
  {
    f32x4 pf[4];
    #pragma unroll
    for (int i = 0; i < 4; i++){
      int fi = tid + i * 256, row = fi >> 5, q = fi & 31;
      pf[i] = ((const f32x4*)x)[(size_t)(r0 + row) * 32 + q];
    }
    #pragma unroll
    for (int i = 0; i < 4; i++){
      int fi = tid + i * 256, row = fi >> 5, q = fi & 31;
      uint2 pk; pk.x = pkt(pf[i][0], pf[i][1]); pk.y = pkt(pf[i][2], pf[i][3]);
      *(uint2*)&aT[row * 136 + q * 4] = pk;
    }
    #pragma unroll
    for (int i = 0; i < 4; i++){
      int fi = 1024 + tid + i * 256, row = fi >> 5, q = fi & 31;
      pf[i] = ((const f32x4*)x)[(size_t)(r0 + row) * 32 + q];
    }
    #pragma unroll
    for (int i = 0; i < 4; i++){
      int fi = 1024 + tid + i * 256, row = fi >> 5, q = fi & 31;
      uint2 pk; pk.x = pkt(pf[i][0], pf[i][1]); pk.y = pkt(pf[i][2], pf[i][3]);
      *(uint2*)&aT[row * 136 + q * 4] = pk;
    }
  }
  __syncthreads();

  f32x4 zero4 = {0.f, 0.f, 0.f, 0.f};
  f32x4 acc[4][4], acc_a[4];
  #pragma unroll
  for (int mf = 0; mf < 4; mf++){
    acc_a[mf] = zero4;
    #pragma unroll
    for (int nf = 0; nf < 4; nf++) acc[mf][nf] = zero4;
  }
  #pragma unroll
  for (int kf = 0; kf < 4; kf++){
    int kb = kf * 32 + hi * 8;
    short8 a[4];
    #pragma unroll
    for (int mf = 0; mf < 4; mf++) a[mf] = *(const short8*)&aT[(mf * 16 + lo) * 136 + kb];
    #pragma unroll
    for (int mf = 0; mf < 4; mf++)
      #pragma unroll
      for (int nf = 0; nf < 4; nf++)
        acc[mf][nf] = __builtin_amdgcn_mfma_f32_16x16x32_bf16(a[mf], B[nf][kf], acc[mf][nf], 0, 0, 0);
    if (w == 0){
      #pragma unroll
      for (int mf = 0; mf < 4; mf++)
        acc_a[mf] = __builtin_amdgcn_mfma_f32_16x16x32_bf16(a[mf], WA[kf], acc_a[mf], 0, 0, 0);
    }
  }

  // ---- coalesced h0 store via LDS stage (two 32-row halves) ----
  unsigned short (*stg)[STG_P] = (unsigned short (*)[STG_P])aT;
  #pragma unroll
  for (int h = 0; h < 2; h++){
    __syncthreads();                 // aT reads (MFMA phase / prev half stores) complete
    #pragma unroll
    for (int mm = 0; mm < 2; mm++){
      int mf = 2 * h + mm;
      #pragma unroll
      for (int nf = 0; nf < 4; nf++)
        #pragma unroll
        for (int rg = 0; rg < 4; rg++){
          int rl = mm * 16 + hi * 4 + rg;          // 0..31 within half
          stg[rl][w * 64 + nf * 16 + lo] = tbf(acc[mf][nf][rg]);
        }
    }
    __syncthreads();
    #pragma unroll
    for (int i = 0; i < 4; i++){
      int fi = tid + i * 256;        // 0..1023
      int rl = fi >> 5, c16 = fi & 31;
      short8 v = *(const short8*)&stg[rl][c16 * 8];
      *(short8*)&h0[(size_t)(r0 + h * 32 + rl) * C0 + c16 * 8] = v;
    }
  }
  // alpha store (cols: lo<4 -> as, lo 4..7 -> ad)
  if (w == 0 && lo < 8){
    #pragma unroll
    for (int mf = 0; mf < 4; mf++)
      #pragma unroll
      for (int rg = 0; rg < 4; rg++){
        int row = r0 + mf * 16 + hi * 4 + rg;
        float v = acc_a[mf][rg];
        if (lo < 4) as0[row * H0_N + lo] = v;
        else if (row < N_DST0) ad0[row * H0_N + (lo - 4)] = v;
      }
  }
}

// ---------------- agg0: per-dst slab load + 1 wave/dst softmax-gather ----------------
__global__ __launch_bounds__(256) void agg0_kernel(
    const unsigned short* __restrict__ h0, const float* __restrict__ as0, const float* __restrict__ ad0,
    const int* __restrict__ bcnt, const int* __restrict__ pairs0,
    const float* __restrict__ bias0, unsigned short* __restrict__ out0)
{
  __shared__ int srtL[4][DCAP0];
  __shared__ f32x4 sp[4][DCAP0];
  int tid = threadIdx.x, w = tid >> 6, t = tid & 63;
  int d = blockIdx.x * 4 + w;

  int deg = bcnt[d]; if (deg > DCAP0) deg = DCAP0;
  int sT = 0;
  if (t < deg){
    sT = pairs0[d * DCAP0 + t];       // coalesced slab read
    srtL[w][t] = sT;
  }
  f32x4 adv = ((const f32x4*)ad0)[d];
  f32x4 asd = ((const f32x4*)as0)[d];
  f32x4 es;
  #pragma unroll
  for (int h = 0; h < 4; h++) es[h] = lrelu(asd[h] + adv[h]);

  // max phase (deg <= 64 -> single pass)
  f32x4 m4 = {-1e30f, -1e30f, -1e30f, -1e30f};
  if (t < deg){
    f32x4 a4 = ((const f32x4*)as0)[sT];
    #pragma unroll
    for (int h = 0; h < 4; h++) m4[h] = lrelu(a4[h] + adv[h]);
  }
  #pragma unroll
  for (int msk = 1; msk < 64; msk <<= 1){
    #pragma unroll
    for (int h = 0; h < 4; h++) m4[h] = fmaxf(m4[h], __shfl_xor(m4[h], msk));
  }
  #pragma unroll
  for (int h = 0; h < 4; h++) m4[h] = fmaxf(m4[h], es[h]);

  // q phase
  f32x4 zl = {0.f, 0.f, 0.f, 0.f};
  if (t < deg){
    f32x4 a4 = ((const f32x4*)as0)[sT];
    f32x4 q4;
    #pragma unroll
    for (int h = 0; h < 4; h++){
      q4[h] = __expf(lrelu(a4[h] + adv[h]) - m4[h]);
      zl[h] += q4[h];
    }
    sp[w][t] = q4;
  }
  asm volatile("s_waitcnt lgkmcnt(0)" ::: "memory");

  // z reduce + self term
  #pragma unroll
  for (int msk = 1; msk < 64; msk <<= 1){
    #pragma unroll
    for (int h = 0; h < 4; h++) zl[h] += __shfl_xor(zl[h], msk);
  }
  #pragma unroll
  for (int h = 0; h < 4; h++) zl[h] += __expf(es[h] - m4[h]);

  // gather with strip-8 preload
  int ht = t >> 4;
  const float* spf = (const float*)&sp[w][0];
  float acc0 = 0.f, acc1 = 0.f, acc2 = 0.f, acc3 = 0.f;
  for (int j0 = 0; j0 < deg; j0 += 8){
    int sj[8]; float pj[8];
    #pragma unroll
    for (int k = 0; k < 8; k++){
      int j = j0 + k;
      bool v = j < deg;
      sj[k] = v ? srtL[w][j] : 0;
      pj[k] = v ? spf[j * 4 + ht] : 0.f;
    }
    u16x4 hv[8];
    #pragma unroll
    for (int k = 0; k < 8; k++) hv[k] = *(const u16x4*)&h0[(size_t)sj[k] * C0 + t * 4];
    #pragma unroll
    for (int k = 0; k < 8; k++){
      acc0 += bf2f(hv[k][0]) * pj[k]; acc1 += bf2f(hv[k][1]) * pj[k];
      acc2 += bf2f(hv[k][2]) * pj[k]; acc3 += bf2f(hv[k][3]) * pj[k];
    }
  }
  // self loop
  float qs = __expf(es[ht] - m4[ht]);
  {
    u16x4 hv = *(const u16x4*)&h0[(size_t)d * C0 + t * 4];
    acc0 += bf2f(hv[0]) * qs; acc1 += bf2f(hv[1]) * qs;
    acc2 += bf2f(hv[2]) * qs; acc3 += bf2f(hv[3]) * qs;
  }
  float rz = 1.f / zl[ht];
  f32x4 b4 = ((const f32x4*)bias0)[t];
  uint2 pk;
  pk.x = pkt(acc0 * rz + b4[0], acc1 * rz + b4[1]);
  pk.y = pkt(acc2 * rz + b4[2], acc3 * rz + b4[3]);
  ((uint2*)out0)[(size_t)d * 64 + t] = pk;
}

// ---------------- BatchNorm stats (bf16 input) ----------------
__global__ void bn_stats(const unsigned short* __restrict__ out0, float* __restrict__ gsum, float* __restrict__ gsq){
  int t = threadIdx.x;
  int r0 = blockIdx.x * 128;
  int rend = r0 + 128; if (rend > N_DST0) rend = N_DST0;
  float s = 0.f, q = 0.f;
  for (int r = r0; r < rend; r++){
    float v = bf2f(out0[(size_t)r * C0 + t]);
    s += v; q += v * v;
  }
  atomicAdd(&gsum[t], s);
  atomicAdd(&gsq[t], q);
}

// ---------------- GEMM1: h1 = relu(bn(out0)) @ W1 + alpha; bn_final folded in ----------------
__global__ __launch_bounds__(256) void gemm1_kernel(
    const unsigned short* __restrict__ out0, const unsigned short* __restrict__ w1t,
    const unsigned short* __restrict__ wa1G,
    const float* __restrict__ gsum, const float* __restrict__ gsq,
    const float* __restrict__ gamma, const float* __restrict__ beta,
    float* __restrict__ h1, float* __restrict__ as1, float* __restrict__ ad1)
{
  __shared__ __align__(16) unsigned short aT[128 * 72];
  __shared__ __align__(16) unsigned short wT[48 * 72];
  __shared__ __align__(16) unsigned short wa1T[16 * 72];
  __shared__ float scL[C0], shL[C0];
  int tid = threadIdx.x;
  int r0 = blockIdx.x * 128;
  int w = tid >> 6, lane = tid & 63, lo = lane & 15, hi = lane >> 4;

  {
    float mu = gsum[tid] * (1.f / N_DST0);
    float var = gsq[tid] * (1.f / N_DST0) - mu * mu;
    float rs = rsqrtf(var + BN_EPS);
    float sc = gamma[tid] * rs;
    scL[tid] = sc;
    shL[tid] = beta[tid] - mu * sc;
  }
  __syncthreads();

  f32x4 zero4 = {0.f, 0.f, 0.f, 0.f};
  f32x4 acc[2][3], acc_a[2];
  #pragma unroll
  for (int mf = 0; mf < 2; mf++){
    acc_a[mf] = zero4;
    #pragma unroll
    for (int nf = 0; nf < 3; nf++) acc[mf][nf] = zero4;
  }

  for (int kc = 0; kc < 4; kc++){
    if (kc) __syncthreads();
    #pragma unroll
    for (int i = 0; i < 8; i++){
      int fi = tid + i * 256;          // 0..2047
      int row = fi >> 4, kq = fi & 15;
      int r = r0 + row;
      u16x4 v = {0,0,0,0};
      if (r < N_DST0) v = ((const u16x4*)out0)[(size_t)r * 64 + kc * 16 + kq];
      f32x4 sc4 = ((const f32x4*)scL)[kc * 16 + kq];
      f32x4 sh4 = ((const f32x4*)shL)[kc * 16 + kq];
      float f[4];
      #pragma unroll
      for (int j = 0; j < 4; j++){
        float u = bf2f(v[j]) * sc4[j] + sh4[j];
        f[j] = u > 0.f ? u : 0.f;
      }
      uint2 pk; pk.x = pkt(f[0], f[1]); pk.y = pkt(f[2], f[3]);
      *(uint2*)&aT[row * 72 + kq * 4] = pk;
    }
    #pragma unroll
    for (int i = 0; i < 3; i++){
      int fi = tid + i * 256;          // 0..767
      int n = fi >> 4, kq = fi & 15;
      *(u16x4*)&wT[n * 72 + kq * 4] = ((const u16x4*)w1t)[n * 64 + kc * 16 + kq];
    }
    {
      int n = tid >> 4, kq = tid & 15;
      u16x4 v = {0,0,0,0};
      if (n < 2) v = ((const u16x4*)wa1G)[n * 64 + kc * 16 + kq];
      *(u16x4*)&wa1T[n * 72 + kq * 4] = v;
    }
    __syncthreads();
    #pragma unroll
    for (int kk = 0; kk < 2; kk++){
      int kb = kk * 32 + hi * 8;
      short8 a[2], bfr[3];
      #pragma unroll
      for (int mf = 0; mf < 2; mf++) a[mf] = *(const short8*)&aT[(w * 32 + mf * 16 + lo) * 72 + kb];
      #pragma unroll
      for (int nf = 0; nf < 3; nf++) bfr[nf] = *(const short8*)&wT[(nf * 16 + lo) * 72 + kb];
      short8 wab = *(const short8*)&wa1T[lo * 72 + kb];
      #pragma unroll
      for (int mf = 0; mf < 2; mf++){
        #pragma unroll
        for (int nf = 0; nf < 3; nf++)
          acc[mf][nf] = __builtin_amdgcn_mfma_f32_16x16x32_bf16(a[mf], bfr[nf], acc[mf][nf], 0, 0, 0);
        acc_a[mf] = __builtin_amdgcn_mfma_f32_16x16x32_bf16(a[mf], wab, acc_a[mf], 0, 0, 0);
      }
    }
  }

  #pragma unroll
  for (int mf = 0; mf < 2; mf++)
    #pragma unroll
    for (int rg = 0; rg < 4; rg++){
      int r = r0 + w * 32 + mf * 16 + hi * 4 + rg;
      if (r < N_DST0){
        #pragma unroll
        for (int nf = 0; nf < 3; nf++)
          h1[(size_t)r * H1W + nf * 16 + lo] = acc[mf][nf][rg];
        if (lo == 0) as1[r] = acc_a[mf][rg];
        else if (lo == 1 && r < N_DST1) ad1[r] = acc_a[mf][rg];
      }
    }
}

// ---------------- agg1: per-dst slab load + 1 wave/dst + log_softmax ----------------
__global__ __launch_bounds__(256) void agg1_kernel(
    const float* __restrict__ h1, const float* __restrict__ as1, const float* __restrict__ ad1,
    const int* __restrict__ bcnt, const int* __restrict__ pairs1,
    const float* __restrict__ bias1, float* __restrict__ out)
{
  __shared__ int srtL[4][DCAP1];
  __shared__ float sp1[4][DCAP1];
  int tid = threadIdx.x, w = tid >> 6, t = tid & 63;
  int d = blockIdx.x * 4 + w;

  int deg = bcnt[N_DST0 + d]; if (deg > DCAP1) deg = DCAP1;
  for (int i = t; i < deg; i += 64) srtL[w][i] = pairs1[d * DCAP1 + i];
  asm volatile("s_waitcnt lgkmcnt(0)" ::: "memory");

  float adv = ad1[d];
  float es = lrelu(as1[d] + adv);

  float m = -1e30f;
  for (int i = t; i < deg; i += 64) m = fmaxf(m, lrelu(as1[srtL[w][i]] + adv));
  #pragma unroll
  for (int msk = 1; msk < 64; msk <<= 1) m = fmaxf(m, __shfl_xor(m, msk));
  m = fmaxf(m, es);

  float zl = 0.f;
  for (int i = t; i < deg; i += 64){
    float q = __expf(lrelu(as1[srtL[w][i]] + adv) - m);
    zl += q;
    sp1[w][i] = q;
  }
  asm volatile("s_waitcnt lgkmcnt(0)" ::: "memory");
  #pragma unroll
  for (int msk = 1; msk < 64; msk <<= 1) zl += __shfl_xor(zl, msk);
  float qs = __expf(es - m);
  float z = zl + qs;

  bool tl = (t < H1W);
  float acc = 0.f;
  for (int j0 = 0; j0 < deg; j0 += 8){
    int sj[8]; float pj[8];
    #pragma unroll
    for (int k = 0; k < 8; k++){
      int j = j0 + k;
      bool v = j < deg;
      sj[k] = v ? srtL[w][j] : 0;
      pj[k] = v ? sp1[w][j] : 0.f;
    }
    float hv[8];
    #pragma unroll
    for (int k = 0; k < 8; k++) hv[k] = tl ? h1[(size_t)sj[k] * H1W + t] : 0.f;
    #pragma unroll
    for (int k = 0; k < 8; k++) acc += pj[k] * hv[k];
  }
  float hs = tl ? h1[(size_t)d * H1W + t] : 0.f;
  acc = (acc + qs * hs) / z;
  float v = acc + ((t < OUTC) ? bias1[t] : 0.f);
  float vm = (t < OUTC) ? v : -1e30f;
  #pragma unroll
  for (int msk = 1; msk < 64; msk <<= 1) vm = fmaxf(vm, __shfl_xor(vm, msk));
  float ex = (t < OUTC) ? __expf(v - vm) : 0.f;
  #pragma unroll
  for (int msk = 1; msk < 64; msk <<= 1) ex += __shfl_xor(ex, msk);
  if (t < OUTC) out[(size_t)d * OUTC + t] = v - vm - __logf(ex);
}

// ---------------- launch ----------------
extern "C" void kernel_launch(void* const* d_in, const int* in_sizes, int n_in,
                              void* d_out, int out_size, void* d_ws, size_t ws_size,
                              hipStream_t stream)
{
  const float* x        = (const float*)d_in[0];
  const float* W0       = (const float*)d_in[1];
  const float* att_src0 = (const float*)d_in[2];
  const float* att_dst0 = (const float*)d_in[3];
  const float* bias0    = (const float*)d_in[4];
  const float* gamma0   = (const float*)d_in[5];
  const float* beta0    = (const float*)d_in[6];
  const float* W1       = (const float*)d_in[7];
  const float* att_src1 = (const float*)d_in[8];
  const float* att_dst1 = (const float*)d_in[9];
  const float* bias1    = (const float*)d_in[10];
  const int* esrc0 = (const int*)d_in[11];
  const int* edst0 = (const int*)d_in[12];
  const int* esrc1 = (const int*)d_in[13];
  const int* edst1 = (const int*)d_in[14];
  float* out = (float*)d_out;

  char* p = (char*)d_ws;
  auto alloc = [&](size_t b) -> char* {
    char* r = p; p += (b + 255) & ~(size_t)255; return r;
  };
  unsigned short* h0   = (unsigned short*)alloc((size_t)N_SRC * C0 * 2);    // 102.4 MB
  unsigned short* out0 = (unsigned short*)alloc((size_t)N_DST0 * C0 * 2);   // 25.6 MB
  unsigned short* wt0  = (unsigned short*)alloc((size_t)C0 * IN_C * 2);
  unsigned short* w1t  = (unsigned short*)alloc((size_t)H1W * C0 * 2);
  unsigned short* waG  = (unsigned short*)alloc((size_t)8 * IN_C * 2);
  unsigned short* wa1G = (unsigned short*)alloc((size_t)2 * C0 * 2);
  float* as0          = (float*)alloc((size_t)N_SRC * H0_N * 4);
  float* ad0          = (float*)alloc((size_t)N_DST0 * H0_N * 4);
  float* h1           = (float*)alloc((size_t)N_DST0 * H1W * 4);
  float* as1          = (float*)alloc((size_t)N_DST0 * 4);
  float* ad1          = (float*)alloc((size_t)N_DST1 * 4);
  int* pairs0         = (int*)alloc((size_t)N_DST0 * DCAP0 * 4);            // 12.8 MB
  int* pairs1         = (int*)alloc((size_t)N_DST1 * DCAP1 * 4);            // 3.84 MB
  // contiguous zero zone
  char* zbase = p;
  int* bcnt   = (int*)alloc((size_t)NSEG * 4);
  float* gsum = (float*)alloc((size_t)C0 * 4);
  float* gsq  = (float*)alloc((size_t)C0 * 4);
  size_t zspan = (size_t)(p - zbase);
  hipMemsetAsync(zbase, 0, zspan, stream);

  // K1: weight prep
  prep_all<<<dim3(182), 256, 0, stream>>>(W0, W1, att_src0, att_dst0, att_src1, att_dst1,
                                          wt0, w1t, waG, wa1G);

  // K2: gemm0 || slab-scatter (period-8 interleave, scatter 8 edges/thread)
  gemm0_bucket_kernel<<<dim3(GRID_K2), 256, 0, stream>>>(
      x, wt0, waG, h0, as0, ad0,
      esrc0, edst0, esrc1, edst1, bcnt, pairs0, pairs1);

  // agg0: 1 wave per dst, coalesced slab read
  agg0_kernel<<<dim3(N_DST0 / 4), 256, 0, stream>>>(h0, as0, ad0, bcnt, pairs0, bias0, out0);

  bn_stats<<<dim3((N_DST0 + 127) / 128), 256, 0, stream>>>(out0, gsum, gsq);

  gemm1_kernel<<<dim3((N_DST0 + 127) / 128), 256, 0, stream>>>(out0, w1t, wa1G,
                                                               gsum, gsq, gamma0, beta0,
                                                               h1, as1, ad1);

  agg1_kernel<<<dim3(N_DST1 / 4), 256, 0, stream>>>(h1, as1, ad1, bcnt, pairs1, bias1, out);
}

// Round 14
// 239.757 us; speedup vs baseline: 1.2460x; 1.2460x over previous
//
#include <hip/hip_runtime.h>
#include <stdint.h>

#define N_SRC  200000
#define N_DST0 50000
#define N_DST1 10000
#define E0_N   800000
#define E1_N   320000
#define E_TOT  (E0_N + E1_N)
#define NSEG   (N_DST0 + N_DST1)
#define IN_C   128
#define HID    64
#define H0_N   4
#define C0     256      // H0*HID
#define OUTC   40
#define H1W    48       // padded h1 width
#define NEG_SLOPE 0.2f
#define BN_EPS 1e-5f

#define DCAP0  64                  // per-dst slab, avg deg 16 (Poisson)
#define DCAP1  96                  // per-dst slab, avg deg 32

#define NB_GEMM (N_SRC / 64)       // 3125
#define NB_SCAT ((E_TOT + 1023) / 1024)   // 1094 (4 edges/thread)
#define GRID_K2 (4 * NB_SCAT)      // 4376: period-4 interleave, slot 3 = scatter

#define NB_PREP   182
#define NB_ZBCNT  ((NSEG + 255) / 256)    // 235
#define NB_ZMISC  2                        // gsum+gsq (512 floats)
#define GRID_PREP (NB_PREP + NB_ZBCNT + NB_ZMISC)

typedef __attribute__((ext_vector_type(8))) short short8;
typedef __attribute__((ext_vector_type(4))) float f32x4;
typedef __attribute__((ext_vector_type(4))) unsigned short u16x4;

__device__ __forceinline__ float bf2f(unsigned short u){
  union{unsigned int i; float f;} v; v.i = ((unsigned int)u) << 16; return v.f;
}
__device__ __forceinline__ unsigned short f2bf(float f){   // RNE (weights only)
  union{float f; unsigned int i;} v; v.f = f;
  unsigned int u = v.i;
  unsigned int r = (u + 0x7FFFu + ((u >> 16) & 1u)) >> 16;
  return (unsigned short)r;
}
// truncate-pack two f32 -> one u32 of 2 bf16
__device__ __forceinline__ unsigned int pkt(float a, float b){
  return (__float_as_uint(a) >> 16) | (__float_as_uint(b) & 0xFFFF0000u);
}
__device__ __forceinline__ unsigned short tbf(float f){
  return (unsigned short)(__float_as_uint(f) >> 16);
}
__device__ __forceinline__ float lrelu(float x){ return x > 0.f ? x : NEG_SLOPE * x; }

// ---------------- K1: weight prep + ws zeroing ----------------
__global__ void prep_all(const float* __restrict__ W0, const float* __restrict__ W1,
                         const float* __restrict__ as0a, const float* __restrict__ ad0a,
                         const float* __restrict__ as1a, const float* __restrict__ ad1a,
                         unsigned short* __restrict__ wt0, unsigned short* __restrict__ w1t,
                         unsigned short* __restrict__ waG, unsigned short* __restrict__ wa1G,
                         int* __restrict__ bcnt, float* __restrict__ gsum, float* __restrict__ gsq)
{
  int b = blockIdx.x, t = threadIdx.x;
  if (b >= NB_PREP){
    int zb = b - NB_PREP;
    if (zb < NB_ZBCNT){
      int i = zb * 256 + t;
      if (i < NSEG) bcnt[i] = 0;
    } else {
      int i = (zb - NB_ZBCNT) * 256 + t;
      if (i < C0){ gsum[i] = 0.f; gsq[i] = 0.f; }
    }
    return;
  }
  if (b < 128){                       // wt0: 256x128
    int idx = b * 256 + t;
    int n = idx / IN_C, k = idx % IN_C;
    wt0[idx] = f2bf(W0[k * C0 + n]);
  } else if (b < 176){                // w1t: 48x256
    int idx = (b - 128) * 256 + t;
    int n = idx / C0, k = idx % C0;
    w1t[idx] = (n < OUTC) ? f2bf(W1[k * OUTC + n]) : (unsigned short)0;
  } else {                            // waG 8x128, wa1G 2x256
    int idx = (b - 176) * 256 + t;
    if (idx < 1024){
      int k = idx >> 3, j = idx & 7, h = j & 3;
      const float* att = (j < 4) ? as0a : ad0a;
      float s = 0.f;
      #pragma unroll
      for (int c = 0; c < HID; c++) s += W0[k * C0 + h * HID + c] * att[h * HID + c];
      waG[j * IN_C + k] = f2bf(s);
    } else if (idx < 1536){
      int r = idx - 1024; int k = r >> 1, j = r & 1;
      const float* att = j ? ad1a : as1a;
      float s = 0.f;
      #pragma unroll
      for (int c = 0; c < OUTC; c++) s += W1[k * OUTC + c] * att[c];
      wa1G[j * C0 + k] = f2bf(s);
    }
  }
}

// ---------------- K2: gemm0 (3/4 of slots) || slab-scatter (1/4, 4 edges/thread) ----------------
__global__ __launch_bounds__(256) void gemm0_bucket_kernel(
    const float* __restrict__ x, const unsigned short* __restrict__ wt0,
    const unsigned short* __restrict__ waG,
    unsigned short* __restrict__ h0, float* __restrict__ as0, float* __restrict__ ad0,
    const int* __restrict__ esrc0, const int* __restrict__ edst0,
    const int* __restrict__ esrc1, const int* __restrict__ edst1,
    int* __restrict__ bcnt, int* __restrict__ pairs0, int* __restrict__ pairs1)
{
  __shared__ __align__(16) unsigned short aT[64 * 136];
  int b = blockIdx.x;
  int tid = threadIdx.x;

  if ((b & 3) == 3){
    // ---- scatter role: 4 edges/thread for MLP ----
    int base = (b >> 2) * 1024 + tid;
    int dk[4], sk[4];
    bool ok[4], l0[4];
    #pragma unroll
    for (int k = 0; k < 4; k++){
      int e = base + k * 256;
      ok[k] = e < E_TOT;
      l0[k] = e < E0_N;
      if (ok[k]){
        if (l0[k]){ dk[k] = edst0[e]; sk[k] = esrc0[e]; }
        else      { int i = e - E0_N; dk[k] = edst1[i]; sk[k] = esrc1[i]; }
      }
    }
    #pragma unroll
    for (int k = 0; k < 4; k++){
      if (ok[k]){
        if (l0[k]){
          int pos = atomicAdd(&bcnt[dk[k]], 1);
          if (pos < DCAP0) pairs0[dk[k] * DCAP0 + pos] = sk[k];
        } else {
          int pos = atomicAdd(&bcnt[N_DST0 + dk[k]], 1);
          if (pos < DCAP1) pairs1[dk[k] * DCAP1 + pos] = sk[k];
        }
      }
    }
    return;
  }
  // ---- gemm role ----
  int g = b - (b >> 2);               // slots 0,1,2 of each 4 -> dense index
  if (g >= NB_GEMM) return;
  int w = tid >> 6, lane = tid & 63, lo = lane & 15, hi = lane >> 4;
  int r0 = g * 64;

  // B fragments: wave w owns head w (cols w*64 .. w*64+63)
  short8 B[4][4];
  #pragma unroll
  for (int nf = 0; nf < 4; nf++)
    #pragma unroll
    for (int kf = 0; kf < 4; kf++)
      B[nf][kf] = *(const short8*)&wt0[(w * 64 + nf * 16 + lo) * IN_C + kf * 32 + hi * 8];
  short8 WA[4];
  {
    short8 z8 = {0,0,0,0,0,0,0,0};
    #pragma unroll
    for (int kf = 0; kf < 4; kf++)
      WA[kf] = (w == 0 && lo < 8) ? *(const short8*)&waG[lo * IN_C + kf * 32 + hi * 8] : z8;
  }
  // stage A in two pf[4] rounds (lower VGPR peak)
  {
    f32x4 pf[4];
    #pragma unroll
    for (int i = 0; i < 4; i++){
      int fi = tid + i * 256, row = fi >> 5, q = fi & 31;
      pf[i] = ((const f32x4*)x)[(size_t)(r0 + row) * 32 + q];
    }
    #pragma unroll
    for (int i = 0; i < 4; i++){
      int fi = tid + i * 256, row = fi >> 5, q = fi & 31;
      uint2 pk; pk.x = pkt(pf[i][0], pf[i][1]); pk.y = pkt(pf[i][2], pf[i][3]);
      *(uint2*)&aT[row * 136 + q * 4] = pk;
    }
    #pragma unroll
    for (int i = 0; i < 4; i++){
      int fi = 1024 + tid + i * 256, row = fi >> 5, q = fi & 31;
      pf[i] = ((const f32x4*)x)[(size_t)(r0 + row) * 32 + q];
    }
    #pragma unroll
    for (int i = 0; i < 4; i++){
      int fi = 1024 + tid + i * 256, row = fi >> 5, q = fi & 31;
      uint2 pk; pk.x = pkt(pf[i][0], pf[i][1]); pk.y = pkt(pf[i][2], pf[i][3]);
      *(uint2*)&aT[row * 136 + q * 4] = pk;
    }
  }
  __syncthreads();

  f32x4 zero4 = {0.f, 0.f, 0.f, 0.f};
  f32x4 acc[4][4], acc_a[4];
  #pragma unroll
  for (int mf = 0; mf < 4; mf++){
    acc_a[mf] = zero4;
    #pragma unroll
    for (int nf = 0; nf < 4; nf++) acc[mf][nf] = zero4;
  }
  #pragma unroll
  for (int kf = 0; kf < 4; kf++){
    int kb = kf * 32 + hi * 8;
    short8 a[4];
    #pragma unroll
    for (int mf = 0; mf < 4; mf++) a[mf] = *(const short8*)&aT[(mf * 16 + lo) * 136 + kb];
    #pragma unroll
    for (int mf = 0; mf < 4; mf++)
      #pragma unroll
      for (int nf = 0; nf < 4; nf++)
        acc[mf][nf] = __builtin_amdgcn_mfma_f32_16x16x32_bf16(a[mf], B[nf][kf], acc[mf][nf], 0, 0, 0);
    if (w == 0){
      #pragma unroll
      for (int mf = 0; mf < 4; mf++)
        acc_a[mf] = __builtin_amdgcn_mfma_f32_16x16x32_bf16(a[mf], WA[kf], acc_a[mf], 0, 0, 0);
    }
  }
  // stores
  #pragma unroll
  for (int mf = 0; mf < 4; mf++)
    #pragma unroll
    for (int rg = 0; rg < 4; rg++){
      int row = r0 + mf * 16 + hi * 4 + rg;
      #pragma unroll
      for (int nf = 0; nf < 4; nf++)
        h0[(size_t)row * C0 + w * 64 + nf * 16 + lo] = tbf(acc[mf][nf][rg]);
    }
  if (w == 0 && lo < 8){
    #pragma unroll
    for (int mf = 0; mf < 4; mf++)
      #pragma unroll
      for (int rg = 0; rg < 4; rg++){
        int row = r0 + mf * 16 + hi * 4 + rg;
        float v = acc_a[mf][rg];
        if (lo < 4) as0[row * H0_N + lo] = v;
        else if (row < N_DST0) ad0[row * H0_N + (lo - 4)] = v;
      }
  }
}

// ---------------- agg0: per-dst slab load + 1 wave/dst softmax-gather ----------------
__global__ __launch_bounds__(256) void agg0_kernel(
    const unsigned short* __restrict__ h0, const float* __restrict__ as0, const float* __restrict__ ad0,
    const int* __restrict__ bcnt, const int* __restrict__ pairs0,
    const float* __restrict__ bias0, unsigned short* __restrict__ out0)
{
  __shared__ int srtL[4][DCAP0];
  __shared__ f32x4 sp[4][DCAP0];
  int tid = threadIdx.x, w = tid >> 6, t = tid & 63;
  int d = blockIdx.x * 4 + w;

  int deg = bcnt[d]; if (deg > DCAP0) deg = DCAP0;
  int sT = 0;
  if (t < deg){
    sT = pairs0[d * DCAP0 + t];       // coalesced slab read
    srtL[w][t] = sT;
  }
  f32x4 adv = ((const f32x4*)ad0)[d];
  f32x4 asd = ((const f32x4*)as0)[d];
  f32x4 es;
  #pragma unroll
  for (int h = 0; h < 4; h++) es[h] = lrelu(asd[h] + adv[h]);

  // max phase (deg <= 64 -> single pass)
  f32x4 m4 = {-1e30f, -1e30f, -1e30f, -1e30f};
  if (t < deg){
    f32x4 a4 = ((const f32x4*)as0)[sT];
    #pragma unroll
    for (int h = 0; h < 4; h++) m4[h] = lrelu(a4[h] + adv[h]);
  }
  #pragma unroll
  for (int msk = 1; msk < 64; msk <<= 1){
    #pragma unroll
    for (int h = 0; h < 4; h++) m4[h] = fmaxf(m4[h], __shfl_xor(m4[h], msk));
  }
  #pragma unroll
  for (int h = 0; h < 4; h++) m4[h] = fmaxf(m4[h], es[h]);

  // q phase
  f32x4 zl = {0.f, 0.f, 0.f, 0.f};
  if (t < deg){
    f32x4 a4 = ((const f32x4*)as0)[sT];
    f32x4 q4;
    #pragma unroll
    for (int h = 0; h < 4; h++){
      q4[h] = __expf(lrelu(a4[h] + adv[h]) - m4[h]);
      zl[h] += q4[h];
    }
    sp[w][t] = q4;
  }
  asm volatile("s_waitcnt lgkmcnt(0)" ::: "memory");

  // z reduce + self term
  #pragma unroll
  for (int msk = 1; msk < 64; msk <<= 1){
    #pragma unroll
    for (int h = 0; h < 4; h++) zl[h] += __shfl_xor(zl[h], msk);
  }
  #pragma unroll
  for (int h = 0; h < 4; h++) zl[h] += __expf(es[h] - m4[h]);

  // gather with strip-8 preload
  int ht = t >> 4;
  const float* spf = (const float*)&sp[w][0];
  float acc0 = 0.f, acc1 = 0.f, acc2 = 0.f, acc3 = 0.f;
  for (int j0 = 0; j0 < deg; j0 += 8){
    int sj[8]; float pj[8];
    #pragma unroll
    for (int k = 0; k < 8; k++){
      int j = j0 + k;
      bool v = j < deg;
      sj[k] = v ? srtL[w][j] : 0;
      pj[k] = v ? spf[j * 4 + ht] : 0.f;
    }
    u16x4 hv[8];
    #pragma unroll
    for (int k = 0; k < 8; k++) hv[k] = *(const u16x4*)&h0[(size_t)sj[k] * C0 + t * 4];
    #pragma unroll
    for (int k = 0; k < 8; k++){
      acc0 += bf2f(hv[k][0]) * pj[k]; acc1 += bf2f(hv[k][1]) * pj[k];
      acc2 += bf2f(hv[k][2]) * pj[k]; acc3 += bf2f(hv[k][3]) * pj[k];
    }
  }
  // self loop
  float qs = __expf(es[ht] - m4[ht]);
  {
    u16x4 hv = *(const u16x4*)&h0[(size_t)d * C0 + t * 4];
    acc0 += bf2f(hv[0]) * qs; acc1 += bf2f(hv[1]) * qs;
    acc2 += bf2f(hv[2]) * qs; acc3 += bf2f(hv[3]) * qs;
  }
  float rz = 1.f / zl[ht];
  f32x4 b4 = ((const f32x4*)bias0)[t];
  uint2 pk;
  pk.x = pkt(acc0 * rz + b4[0], acc1 * rz + b4[1]);
  pk.y = pkt(acc2 * rz + b4[2], acc3 * rz + b4[3]);
  ((uint2*)out0)[(size_t)d * 64 + t] = pk;
}

// ---------------- BatchNorm stats (bf16 input) ----------------
__global__ void bn_stats(const unsigned short* __restrict__ out0, float* __restrict__ gsum, float* __restrict__ gsq){
  int t = threadIdx.x;
  int r0 = blockIdx.x * 128;
  int rend = r0 + 128; if (rend > N_DST0) rend = N_DST0;
  float s = 0.f, q = 0.f;
  for (int r = r0; r < rend; r++){
    float v = bf2f(out0[(size_t)r * C0 + t]);
    s += v; q += v * v;
  }
  atomicAdd(&gsum[t], s);
  atomicAdd(&gsq[t], q);
}

// ---------------- GEMM1: h1 = relu(bn(out0)) @ W1 + alpha; bn_final folded in ----------------
__global__ __launch_bounds__(256) void gemm1_kernel(
    const unsigned short* __restrict__ out0, const unsigned short* __restrict__ w1t,
    const unsigned short* __restrict__ wa1G,
    const float* __restrict__ gsum, const float* __restrict__ gsq,
    const float* __restrict__ gamma, const float* __restrict__ beta,
    float* __restrict__ h1, float* __restrict__ as1, float* __restrict__ ad1)
{
  __shared__ __align__(16) unsigned short aT[128 * 72];
  __shared__ __align__(16) unsigned short wT[48 * 72];
  __shared__ __align__(16) unsigned short wa1T[16 * 72];
  __shared__ float scL[C0], shL[C0];
  int tid = threadIdx.x;
  int r0 = blockIdx.x * 128;
  int w = tid >> 6, lane = tid & 63, lo = lane & 15, hi = lane >> 4;

  {
    float mu = gsum[tid] * (1.f / N_DST0);
    float var = gsq[tid] * (1.f / N_DST0) - mu * mu;
    float rs = rsqrtf(var + BN_EPS);
    float sc = gamma[tid] * rs;
    scL[tid] = sc;
    shL[tid] = beta[tid] - mu * sc;
  }
  __syncthreads();

  f32x4 zero4 = {0.f, 0.f, 0.f, 0.f};
  f32x4 acc[2][3], acc_a[2];
  #pragma unroll
  for (int mf = 0; mf < 2; mf++){
    acc_a[mf] = zero4;
    #pragma unroll
    for (int nf = 0; nf < 3; nf++) acc[mf][nf] = zero4;
  }

  for (int kc = 0; kc < 4; kc++){
    if (kc) __syncthreads();
    #pragma unroll
    for (int i = 0; i < 8; i++){
      int fi = tid + i * 256;          // 0..2047
      int row = fi >> 4, kq = fi & 15;
      int r = r0 + row;
      u16x4 v = {0,0,0,0};
      if (r < N_DST0) v = ((const u16x4*)out0)[(size_t)r * 64 + kc * 16 + kq];
      f32x4 sc4 = ((const f32x4*)scL)[kc * 16 + kq];
      f32x4 sh4 = ((const f32x4*)shL)[kc * 16 + kq];
      float f[4];
      #pragma unroll
      for (int j = 0; j < 4; j++){
        float u = bf2f(v[j]) * sc4[j] + sh4[j];
        f[j] = u > 0.f ? u : 0.f;
      }
      uint2 pk; pk.x = pkt(f[0], f[1]); pk.y = pkt(f[2], f[3]);
      *(uint2*)&aT[row * 72 + kq * 4] = pk;
    }
    #pragma unroll
    for (int i = 0; i < 3; i++){
      int fi = tid + i * 256;          // 0..767
      int n = fi >> 4, kq = fi & 15;
      *(u16x4*)&wT[n * 72 + kq * 4] = ((const u16x4*)w1t)[n * 64 + kc * 16 + kq];
    }
    {
      int n = tid >> 4, kq = tid & 15;
      u16x4 v = {0,0,0,0};
      if (n < 2) v = ((const u16x4*)wa1G)[n * 64 + kc * 16 + kq];
      *(u16x4*)&wa1T[n * 72 + kq * 4] = v;
    }
    __syncthreads();
    #pragma unroll
    for (int kk = 0; kk < 2; kk++){
      int kb = kk * 32 + hi * 8;
      short8 a[2], bfr[3];
      #pragma unroll
      for (int mf = 0; mf < 2; mf++) a[mf] = *(const short8*)&aT[(w * 32 + mf * 16 + lo) * 72 + kb];
      #pragma unroll
      for (int nf = 0; nf < 3; nf++) bfr[nf] = *(const short8*)&wT[(nf * 16 + lo) * 72 + kb];
      short8 wab = *(const short8*)&wa1T[lo * 72 + kb];
      #pragma unroll
      for (int mf = 0; mf < 2; mf++){
        #pragma unroll
        for (int nf = 0; nf < 3; nf++)
          acc[mf][nf] = __builtin_amdgcn_mfma_f32_16x16x32_bf16(a[mf], bfr[nf], acc[mf][nf], 0, 0, 0);
        acc_a[mf] = __builtin_amdgcn_mfma_f32_16x16x32_bf16(a[mf], wab, acc_a[mf], 0, 0, 0);
      }
    }
  }

  #pragma unroll
  for (int mf = 0; mf < 2; mf++)
    #pragma unroll
    for (int rg = 0; rg < 4; rg++){
      int r = r0 + w * 32 + mf * 16 + hi * 4 + rg;
      if (r < N_DST0){
        #pragma unroll
        for (int nf = 0; nf < 3; nf++)
          h1[(size_t)r * H1W + nf * 16 + lo] = acc[mf][nf][rg];
        if (lo == 0) as1[r] = acc_a[mf][rg];
        else if (lo == 1 && r < N_DST1) ad1[r] = acc_a[mf][rg];
      }
    }
}

// ---------------- agg1: per-dst slab load + 1 wave/dst + log_softmax ----------------
__global__ __launch_bounds__(256) void agg1_kernel(
    const float* __restrict__ h1, const float* __restrict__ as1, const float* __restrict__ ad1,
    const int* __restrict__ bcnt, const int* __restrict__ pairs1,
    const float* __restrict__ bias1, float* __restrict__ out)
{
  __shared__ int srtL[4][DCAP1];
  __shared__ float sp1[4][DCAP1];
  int tid = threadIdx.x, w = tid >> 6, t = tid & 63;
  int d = blockIdx.x * 4 + w;

  int deg = bcnt[N_DST0 + d]; if (deg > DCAP1) deg = DCAP1;
  for (int i = t; i < deg; i += 64) srtL[w][i] = pairs1[d * DCAP1 + i];
  asm volatile("s_waitcnt lgkmcnt(0)" ::: "memory");

  float adv = ad1[d];
  float es = lrelu(as1[d] + adv);

  float m = -1e30f;
  for (int i = t; i < deg; i += 64) m = fmaxf(m, lrelu(as1[srtL[w][i]] + adv));
  #pragma unroll
  for (int msk = 1; msk < 64; msk <<= 1) m = fmaxf(m, __shfl_xor(m, msk));
  m = fmaxf(m, es);

  float zl = 0.f;
  for (int i = t; i < deg; i += 64){
    float q = __expf(lrelu(as1[srtL[w][i]] + adv) - m);
    zl += q;
    sp1[w][i] = q;
  }
  asm volatile("s_waitcnt lgkmcnt(0)" ::: "memory");
  #pragma unroll
  for (int msk = 1; msk < 64; msk <<= 1) zl += __shfl_xor(zl, msk);
  float qs = __expf(es - m);
  float z = zl + qs;

  bool tl = (t < H1W);
  float acc = 0.f;
  for (int j0 = 0; j0 < deg; j0 += 8){
    int sj[8]; float pj[8];
    #pragma unroll
    for (int k = 0; k < 8; k++){
      int j = j0 + k;
      bool v = j < deg;
      sj[k] = v ? srtL[w][j] : 0;
      pj[k] = v ? sp1[w][j] : 0.f;
    }
    float hv[8];
    #pragma unroll
    for (int k = 0; k < 8; k++) hv[k] = tl ? h1[(size_t)sj[k] * H1W + t] : 0.f;
    #pragma unroll
    for (int k = 0; k < 8; k++) acc += pj[k] * hv[k];
  }
  float hs = tl ? h1[(size_t)d * H1W + t] : 0.f;
  acc = (acc + qs * hs) / z;
  float v = acc + ((t < OUTC) ? bias1[t] : 0.f);
  float vm = (t < OUTC) ? v : -1e30f;
  #pragma unroll
  for (int msk = 1; msk < 64; msk <<= 1) vm = fmaxf(vm, __shfl_xor(vm, msk));
  float ex = (t < OUTC) ? __expf(v - vm) : 0.f;
  #pragma unroll
  for (int msk = 1; msk < 64; msk <<= 1) ex += __shfl_xor(ex, msk);
  if (t < OUTC) out[(size_t)d * OUTC + t] = v - vm - __logf(ex);
}

// ---------------- launch ----------------
extern "C" void kernel_launch(void* const* d_in, const int* in_sizes, int n_in,
                              void* d_out, int out_size, void* d_ws, size_t ws_size,
                              hipStream_t stream)
{
  const float* x        = (const float*)d_in[0];
  const float* W0       = (const float*)d_in[1];
  const float* att_src0 = (const float*)d_in[2];
  const float* att_dst0 = (const float*)d_in[3];
  const float* bias0    = (const float*)d_in[4];
  const float* gamma0   = (const float*)d_in[5];
  const float* beta0    = (const float*)d_in[6];
  const float* W1       = (const float*)d_in[7];
  const float* att_src1 = (const float*)d_in[8];
  const float* att_dst1 = (const float*)d_in[9];
  const float* bias1    = (const float*)d_in[10];
  const int* esrc0 = (const int*)d_in[11];
  const int* edst0 = (const int*)d_in[12];
  const int* esrc1 = (const int*)d_in[13];
  const int* edst1 = (const int*)d_in[14];
  float* out = (float*)d_out;

  char* p = (char*)d_ws;
  auto alloc = [&](size_t b) -> char* {
    char* r = p; p += (b + 255) & ~(size_t)255; return r;
  };
  unsigned short* h0   = (unsigned short*)alloc((size_t)N_SRC * C0 * 2);    // 102.4 MB
  unsigned short* out0 = (unsigned short*)alloc((size_t)N_DST0 * C0 * 2);   // 25.6 MB
  unsigned short* wt0  = (unsigned short*)alloc((size_t)C0 * IN_C * 2);
  unsigned short* w1t  = (unsigned short*)alloc((size_t)H1W * C0 * 2);
  unsigned short* waG  = (unsigned short*)alloc((size_t)8 * IN_C * 2);
  unsigned short* wa1G = (unsigned short*)alloc((size_t)2 * C0 * 2);
  float* as0          = (float*)alloc((size_t)N_SRC * H0_N * 4);
  float* ad0          = (float*)alloc((size_t)N_DST0 * H0_N * 4);
  float* h1           = (float*)alloc((size_t)N_DST0 * H1W * 4);
  float* as1          = (float*)alloc((size_t)N_DST0 * 4);
  float* ad1          = (float*)alloc((size_t)N_DST1 * 4);
  int* pairs0         = (int*)alloc((size_t)N_DST0 * DCAP0 * 4);            // 12.8 MB
  int* pairs1         = (int*)alloc((size_t)N_DST1 * DCAP1 * 4);            // 3.84 MB
  int* bcnt           = (int*)alloc((size_t)NSEG * 4);
  float* gsum         = (float*)alloc((size_t)C0 * 4);
  float* gsq          = (float*)alloc((size_t)C0 * 4);

  // K1: weight prep + zero bcnt/gsum/gsq (no separate memset pass)
  prep_all<<<dim3(GRID_PREP), 256, 0, stream>>>(W0, W1, att_src0, att_dst0, att_src1, att_dst1,
                                                wt0, w1t, waG, wa1G, bcnt, gsum, gsq);

  // K2: gemm0 || slab-scatter (period-4 interleave, scatter 4 edges/thread)
  gemm0_bucket_kernel<<<dim3(GRID_K2), 256, 0, stream>>>(
      x, wt0, waG, h0, as0, ad0,
      esrc0, edst0, esrc1, edst1, bcnt, pairs0, pairs1);

  // agg0: 1 wave per dst, coalesced slab read
  agg0_kernel<<<dim3(N_DST0 / 4), 256, 0, stream>>>(h0, as0, ad0, bcnt, pairs0, bias0, out0);

  bn_stats<<<dim3((N_DST0 + 127) / 128), 256, 0, stream>>>(out0, gsum, gsq);

  gemm1_kernel<<<dim3((N_DST0 + 127) / 128), 256, 0, stream>>>(out0, w1t, wa1G,
                                                               gsum, gsq, gamma0, beta0,
                                                               h1, as1, ad1);

  agg1_kernel<<<dim3(N_DST1 / 4), 256, 0, stream>>>(h1, as1, ad1, bcnt, pairs1, bias1, out);
}